// Round 6
// baseline (422.459 us; speedup 1.0000x reference)
//
#include <hip/hip_runtime.h>
#include <hip/hip_bf16.h>

// RelativeAttention: out = ((softmax(((QK^T)*s + Q.rel)*s with mask) V) Wo + bo
// B=4 S=1024 D=1024 H=16 dk=64.  All matmuls in bf16 MFMA (16x16x32), f32 accum.

typedef unsigned short u16;
typedef unsigned int u32;
typedef unsigned long long u64;
typedef __attribute__((ext_vector_type(8))) short bf16x8;
typedef __attribute__((ext_vector_type(4))) float f32x4;

#define SB 1024
#define DM 1024
#define NHD 16
#define DKH 64
#define NBATCH 4

// pin point: loads above cannot sink below; loads below cannot hoist above
#define PIN() do { __builtin_amdgcn_sched_barrier(0); asm volatile("" ::: "memory"); } while (0)

__device__ __forceinline__ u16 f2bf(float x) {
  union { __hip_bfloat16 b; u16 u; } c;
  c.b = __float2bfloat16(x);
  return c.u;
}

__device__ __forceinline__ f32x4 mfma16(bf16x8 a, bf16x8 b, f32x4 c) {
  return __builtin_amdgcn_mfma_f32_16x16x32_bf16(a, b, c, 0, 0, 0);
}

__device__ __forceinline__ bf16x8 cvt8r(float4 v0, float4 v1) {
  bf16x8 r;
  r[0] = (short)f2bf(v0.x); r[1] = (short)f2bf(v0.y);
  r[2] = (short)f2bf(v0.z); r[3] = (short)f2bf(v0.w);
  r[4] = (short)f2bf(v1.x); r[5] = (short)f2bf(v1.y);
  r[6] = (short)f2bf(v1.z); r[7] = (short)f2bf(v1.w);
  return r;
}

// ---------------- f32 -> bf16 for the 3 input activations ----------------
__global__ void ra_convert_in(const float* __restrict__ q, const float* __restrict__ k,
                              const float* __restrict__ v,
                              u16* __restrict__ Xq, u16* __restrict__ Xk, u16* __restrict__ Xv)
{
  const int z = blockIdx.y;
  const float* src = (z == 0) ? q : (z == 1) ? k : v;
  u16* dst = (z == 0) ? Xq : (z == 1) ? Xk : Xv;
  const int n4 = NBATCH * SB * DM / 4;
  int idx = blockIdx.x * blockDim.x + threadIdx.x;
  int stride = gridDim.x * blockDim.x;
  for (int i = idx; i < n4; i += stride) {
    float4 v4 = *((const float4*)src + i);
    uint2 o;
    o.x = (u32)f2bf(v4.x) | ((u32)f2bf(v4.y) << 16);
    o.y = (u32)f2bf(v4.z) | ((u32)f2bf(v4.w) << 16);
    *((uint2*)dst + i) = o;
  }
}

// ---------------- W (f32 [k][n]) -> W^T (bf16 [n][k]) ----------------
__global__ void ra_transpose_w(const float* __restrict__ Wq, const float* __restrict__ Wk,
                               const float* __restrict__ Wv, const float* __restrict__ Wo,
                               u16* __restrict__ WqT, u16* __restrict__ WkT,
                               u16* __restrict__ WvT, u16* __restrict__ WoT)
{
  const int z = blockIdx.z;
  const float* W = (z == 0) ? Wq : (z == 1) ? Wk : (z == 2) ? Wv : Wo;
  u16* WT = (z == 0) ? WqT : (z == 1) ? WkT : (z == 2) ? WvT : WoT;
  __shared__ float tile[32][33];
  const int x0 = blockIdx.x * 32, y0 = blockIdx.y * 32;
  const int tx = threadIdx.x, ty = threadIdx.y;
#pragma unroll
  for (int yy = 0; yy < 4; ++yy) {
    int r = ty + yy * 8;
    tile[r][tx] = W[(size_t)(y0 + r) * DM + x0 + tx];
  }
  __syncthreads();
#pragma unroll
  for (int yy = 0; yy < 4; ++yy) {
    int r = ty + yy * 8;
    WT[(size_t)(x0 + r) * DM + y0 + tx] = f2bf(tile[tx][r]);
  }
}

// ---------------- shared 128x128x1024 bf16 GEMM core ----------------
__device__ __forceinline__ void gemm_core_128(const u16* __restrict__ A, const u16* __restrict__ Bt,
                                              int bm0, int bn0, u16* sh, f32x4 (&acc)[4][4])
{
  u16* As = sh;             // [128][72]
  u16* Bs = sh + 128 * 72;  // [128][72]
  const int tid = threadIdx.x;
  const int lane = tid & 63, wid = tid >> 6;
  const int l15 = lane & 15, l4 = lane >> 4;
  const int wr = (wid >> 1) * 64, wc = (wid & 1) * 64;
  for (int k0 = 0; k0 < DM; k0 += 64) {
#pragma unroll
    for (int it = 0; it < 4; ++it) {
      int c = tid + it * 256;
      int rw = c >> 3, kc = c & 7;
      *(uint4*)(As + rw * 72 + kc * 8) = *(const uint4*)(A + (size_t)(bm0 + rw) * DM + k0 + kc * 8);
      *(uint4*)(Bs + rw * 72 + kc * 8) = *(const uint4*)(Bt + (size_t)(bn0 + rw) * DM + k0 + kc * 8);
    }
    __syncthreads();
#pragma unroll
    for (int kf = 0; kf < 2; ++kf) {
      bf16x8 a[4], b[4];
#pragma unroll
      for (int mf = 0; mf < 4; ++mf)
        a[mf] = *(const bf16x8*)(As + (wr + mf * 16 + l15) * 72 + kf * 32 + l4 * 8);
#pragma unroll
      for (int nf = 0; nf < 4; ++nf)
        b[nf] = *(const bf16x8*)(Bs + (wc + nf * 16 + l15) * 72 + kf * 32 + l4 * 8);
#pragma unroll
      for (int mf = 0; mf < 4; ++mf)
#pragma unroll
        for (int nf = 0; nf < 4; ++nf)
          acc[mf][nf] = mfma16(a[mf], b[nf], acc[mf][nf]);
    }
    __syncthreads();
  }
}

// ---------------- projections: q/k -> [bh][s][dk], v -> [bh][dk][s] ----------------
__global__ __launch_bounds__(256, 2)
void ra_proj_gemm(const u16* __restrict__ Xq, const u16* __restrict__ Xk, const u16* __restrict__ Xv,
                  const u16* __restrict__ WqT, const u16* __restrict__ WkT, const u16* __restrict__ WvT,
                  const float* __restrict__ bq, const float* __restrict__ bk, const float* __restrict__ bv,
                  u16* __restrict__ q_ws, u16* __restrict__ k_ws, u16* __restrict__ vT_ws)
{
  __shared__ alignas(16) u16 sh[128 * 72 * 2];
  const int mode = blockIdx.z;
  const u16* A  = (mode == 0) ? Xq : (mode == 1) ? Xk : Xv;
  const u16* Bt = (mode == 0) ? WqT : (mode == 1) ? WkT : WvT;
  const float* bias = (mode == 0) ? bq : (mode == 1) ? bk : bv;
  const int bm0 = blockIdx.x * 128, bn0 = blockIdx.y * 128;
  f32x4 acc[4][4] = {};
  gemm_core_128(A, Bt, bm0, bn0, sh, acc);
  const int tid = threadIdx.x;
  const int lane = tid & 63, wid = tid >> 6;
  const int l15 = lane & 15, l4 = lane >> 4;
  const int wr = (wid >> 1) * 64, wc = (wid & 1) * 64;
  const int b_idx = bm0 >> 10;
  const int srow0 = bm0 & (SB - 1);
  if (mode < 2) {
    u16* outp = (mode == 0) ? q_ws : k_ws;
#pragma unroll
    for (int nf = 0; nf < 4; ++nf) {
      int nn = bn0 + wc + nf * 16 + l15;
      float bv_ = bias[nn];
      int h = nn >> 6, d = nn & 63;
#pragma unroll
      for (int mf = 0; mf < 4; ++mf)
#pragma unroll
        for (int r = 0; r < 4; ++r) {
          int m = wr + mf * 16 + l4 * 4 + r;
          outp[((size_t)(b_idx * NHD + h) * SB + srow0 + m) * DKH + d] = f2bf(acc[mf][nf][r] + bv_);
        }
    }
  } else {
    u16* ct = sh;  // [128][136]
#pragma unroll
    for (int nf = 0; nf < 4; ++nf) {
      int nl = wc + nf * 16 + l15;
      float bv_ = bias[bn0 + nl];
#pragma unroll
      for (int mf = 0; mf < 4; ++mf)
#pragma unroll
        for (int r = 0; r < 4; ++r) {
          int m = wr + mf * 16 + l4 * 4 + r;
          ct[nl * 136 + m] = f2bf(acc[mf][nf][r] + bv_);
        }
    }
    __syncthreads();
#pragma unroll
    for (int it = 0; it < 8; ++it) {
      int c = tid + it * 256;
      int n = c >> 4, mc2 = c & 15;
      uint4 v = *(const uint4*)(ct + n * 136 + mc2 * 8);
      int nn = bn0 + n;
      int h = nn >> 6, d = nn & 63;
      *(uint4*)(vT_ws + ((size_t)(b_idx * NHD + h) * DKH + d) * SB + srow0 + mc2 * 8) = v;
    }
  }
}

// ---------------- final projection: out = x @ Wo + bo (f32 out) ----------------
__global__ __launch_bounds__(256, 2)
void ra_out_gemm(const u16* __restrict__ X, const u16* __restrict__ WoT,
                 const float* __restrict__ bo, float* __restrict__ out)
{
  __shared__ alignas(16) u16 sh[128 * 72 * 2];
  const int bm0 = blockIdx.x * 128, bn0 = blockIdx.y * 128;
  f32x4 acc[4][4] = {};
  gemm_core_128(X, WoT, bm0, bn0, sh, acc);
  const int tid = threadIdx.x;
  const int lane = tid & 63, wid = tid >> 6;
  const int l15 = lane & 15, l4 = lane >> 4;
  const int wr = (wid >> 1) * 64, wc = (wid & 1) * 64;
#pragma unroll
  for (int nf = 0; nf < 4; ++nf) {
    int nn = bn0 + wc + nf * 16 + l15;
    float bv_ = bo[nn];
#pragma unroll
    for (int mf = 0; mf < 4; ++mf)
#pragma unroll
      for (int r = 0; r < 4; ++r) {
        int m = wr + mf * 16 + l4 * 4 + r;
        out[(size_t)(bm0 + m) * DM + nn] = acc[mf][nf][r] + bv_;
      }
  }
}

// ---------------- mask -> bitmask (1 bit per j) ----------------
__global__ __launch_bounds__(256)
void ra_mask_pack(const int* __restrict__ mask, u32* __restrict__ mb)
{
  const size_t t = (size_t)blockIdx.x * 256 + threadIdx.x;  // 4M threads
  const int lane = threadIdx.x & 63;
  u64 b = __ballot(mask[t] != 0);
  if (lane == 0) *(u64*)(mb + (t >> 6) * 2) = b;
}

// ---------------- fused attention v6 ----------------
// Block = 16 waves (1024 thr) = (i-tile 16, batch g).  Wave w owns head bh=w
// (s1 + PV, K/V direct to regs) and i-plane i=i0+w (s2 compute).  s2 is the only
// cross-wave data: exchanged via 18.7KB double-buffered fp16 LDS tile, ONE
// barrier per j-16 iteration.  Swapped PV keeps softmax state per-lane (lane
// l15 = i) end-to-end: no f shfls, no epilogue shfls.  Mask as bitmask.
__global__ __launch_bounds__(1024, 1)
void ra_attn(const u16* __restrict__ q_ws, const u16* __restrict__ k_ws,
             const u16* __restrict__ vT_ws, const u32* __restrict__ mb,
             const float* __restrict__ rel, u16* __restrict__ x_ws)
{
  // s2t[buf][i][bh][j]: halves, bh-stride 18, i-stride 292 (bank-spread)
  __shared__ _Float16 s2t[2][16 * 292 + 8];

  const int tid = threadIdx.x, wid = tid >> 6, lane = tid & 63;
  const int l15 = lane & 15, l4 = lane >> 4;
  const int g = blockIdx.y, i0 = blockIdx.x * 16;
  const int bh_g = g * NHD + wid;                  // this wave's head
  const float scl1 = 0.125f, scl2 = 0.015625f;     // 1/sqrt(dk), 1/dk

  // ---- persistent q fragments ----
  bf16x8 q1[2], q2[2];
#pragma unroll
  for (int kf = 0; kf < 2; ++kf) {
    // s1 B-frag: Q[n=i=l15][k=d]
    q1[kf] = *(const bf16x8*)(q_ws + ((size_t)bh_g * SB + i0 + l15) * DKH + kf * 32 + l4 * 8);
    // s2 B-frag: Q[n=bh=l15][k=d] at i = i0 + wid
    q2[kf] = *(const bf16x8*)(q_ws + ((size_t)(g * NHD + l15) * SB + i0 + wid) * DKH + kf * 32 + l4 * 8);
  }

  // ---- loop-carried single-set prefetch registers ----
  bf16x8 ka[2];        // K A-frag: K[m=j=l15][k=d]
  float4 rr[4];        // rel f32: rel[i0+wid][jb+l15][d]
  uint2  vb2[4];       // V: vT[d=df*16+l15][jb + l4*4 .. +3]
  u32    mw;           // mask bits for row i=l15, j word jt>>1

  const u16* kbase = k_ws + (size_t)bh_g * SB * DKH;
  const u16* vbase = vT_ws + (size_t)bh_g * DKH * SB;
  const float* rbase = rel + (size_t)(i0 + wid) * SB * DKH;
  const u32* mbase = mb + ((size_t)g * SB + i0 + l15) * 32;

  // prologue: tile 0
#pragma unroll
  for (int kf = 0; kf < 2; ++kf)
    ka[kf] = *(const bf16x8*)(kbase + (size_t)l15 * DKH + kf * 32 + l4 * 8);
  {
    const float* rp = rbase + (size_t)l15 * DKH + l4 * 8;
    rr[0] = *(const float4*)rp;       rr[1] = *(const float4*)(rp + 4);
    rr[2] = *(const float4*)(rp + 32); rr[3] = *(const float4*)(rp + 36);
  }
#pragma unroll
  for (int df = 0; df < 4; ++df)
    vb2[df] = *(const uint2*)(vbase + (size_t)(df * 16 + l15) * SB + l4 * 4);
  mw = mbase[0];
  PIN();

  f32x4 acc_o[4] = {};
  float m_run = -1e30f, l_run = 0.f;

  for (int jt = 0; jt < 64; ++jt) {
    const int jb = jt * 16;
    const int jbn = (jt < 63) ? jb + 16 : jb;
    const int cur = jt & 1;

    // ---- s2 = mfma(A=rel_j, B=q2_bh): D[j][bh], lane l15 = bh, rows j = l4*4+r ----
    {
      bf16x8 rb0 = cvt8r(rr[0], rr[1]);
      bf16x8 rb1 = cvt8r(rr[2], rr[3]);
      f32x4 t = {};
      t = mfma16(rb0, q2[0], t);
      t = mfma16(rb1, q2[1], t);
      union { _Float16 h[4]; uint2 u; } w;
#pragma unroll
      for (int r = 0; r < 4; ++r) w.h[r] = (_Float16)(t[r] * scl1);
      *(uint2*)&s2t[cur][wid * 292 + l15 * 18 + l4 * 4] = w.u;
    }
    // reissue rel(jt+1)
    {
      const float* rp = rbase + (size_t)(jbn + l15) * DKH + l4 * 8;
      rr[0] = *(const float4*)rp;       rr[1] = *(const float4*)(rp + 4);
      rr[2] = *(const float4*)(rp + 32); rr[3] = *(const float4*)(rp + 36);
    }
    PIN();

    // ---- s1 = mfma(A=K_j, B=q1_i): D[j][i], lane l15 = i, j = l4*4+r ----
    f32x4 sc1 = {};
    sc1 = mfma16(ka[0], q1[0], sc1);
    sc1 = mfma16(ka[1], q1[1], sc1);
    // reissue K(jt+1)
#pragma unroll
    for (int kf = 0; kf < 2; ++kf)
      ka[kf] = *(const bf16x8*)(kbase + (size_t)(jbn + l15) * DKH + kf * 32 + l4 * 8);
    PIN();

    __syncthreads();  // s2t[cur] visible (dbuf -> one barrier/iter is safe)

    // ---- softmax: row i = l15, j-chunk l4*4+r; state fully per-lane ----
    float fsc;
    bf16x8 pa;
    {
      uint2 s2u = *(const uint2*)&s2t[cur][l15 * 292 + wid * 18 + l4 * 4];
      union { uint2 u; _Float16 h[4]; } s2c; s2c.u = s2u;
      const int mbit = (jt & 1) * 16 + l4 * 4;
      float sv[4];
#pragma unroll
      for (int r = 0; r < 4; ++r) {
        float v = sc1[r] * scl2 + (float)s2c.h[r];
        sv[r] = ((mw >> (mbit + r)) & 1u) ? v : -1e9f;
      }
      float tmax = fmaxf(fmaxf(sv[0], sv[1]), fmaxf(sv[2], sv[3]));
      tmax = fmaxf(tmax, __shfl_xor(tmax, 16));
      tmax = fmaxf(tmax, __shfl_xor(tmax, 32));
      const float m_new = fmaxf(m_run, tmax);
      fsc = __expf(m_run - m_new);
      float p0 = __expf(sv[0] - m_new), p1 = __expf(sv[1] - m_new);
      float p2 = __expf(sv[2] - m_new), p3 = __expf(sv[3] - m_new);
      float psum = p0 + p1 + p2 + p3;
      psum += __shfl_xor(psum, 16);
      psum += __shfl_xor(psum, 32);
      l_run = l_run * fsc + psum;
      m_run = m_new;
      union { bf16x8 v; u32 w[4]; } pk;
      pk.w[0] = (u32)f2bf(p0) | ((u32)f2bf(p1) << 16);
      pk.w[1] = (u32)f2bf(p2) | ((u32)f2bf(p3) << 16);
      pk.w[2] = 0; pk.w[3] = 0;
      pa = pk.v;
    }

    // ---- PV (swapped): O^T[d][i] = mfma(A=V[d][j], B=P[i][j]); lane l15 = i ----
#pragma unroll
    for (int df = 0; df < 4; ++df) {
      union { bf16x8 v; uint2 q[2]; } vv;
      vv.q[0] = vb2[df];
      vv.q[1] = make_uint2(0, 0);
      f32x4 c = acc_o[df];
      c[0] *= fsc; c[1] *= fsc; c[2] *= fsc; c[3] *= fsc;
      acc_o[df] = mfma16(vv.v, pa, c);
    }
    // reissue V(jt+1), mask
#pragma unroll
    for (int df = 0; df < 4; ++df)
      vb2[df] = *(const uint2*)(vbase + (size_t)(df * 16 + l15) * SB + jbn + l4 * 4);
    mw = mbase[(jt + 1 < 64) ? ((jt + 1) >> 1) : 31];
    PIN();
  }

  // ---- epilogue: per-lane normalize (row i = l15), write x bf16 8B/lane ----
  const float inv = 1.f / l_run;
#pragma unroll
  for (int df = 0; df < 4; ++df) {
    union { u16 h[4]; uint2 u; } o;
#pragma unroll
    for (int r = 0; r < 4; ++r) o.h[r] = f2bf(acc_o[df][r] * inv);
    *(uint2*)(x_ws + ((size_t)g * SB + i0 + l15) * DM + wid * DKH + df * 16 + l4 * 4) = o.u;
  }
}

// ---------------- launch ----------------
extern "C" void kernel_launch(void* const* d_in, const int* in_sizes, int n_in,
                              void* d_out, int out_size, void* d_ws, size_t ws_size,
                              hipStream_t stream) {
  const float* query = (const float*)d_in[0];
  const float* key_  = (const float*)d_in[1];
  const float* value = (const float*)d_in[2];
  const int*   mask  = (const int*)d_in[3];
  const float* rel   = (const float*)d_in[4];
  const float* Wq = (const float*)d_in[5];
  const float* Wk = (const float*)d_in[6];
  const float* Wv = (const float*)d_in[7];
  const float* Wo = (const float*)d_in[8];
  const float* bq = (const float*)d_in[9];
  const float* bk = (const float*)d_in[10];
  const float* bv = (const float*)d_in[11];
  const float* bo = (const float*)d_in[12];
  float* out = (float*)d_out;
  char* ws = (char*)d_ws;

  u16* Xq   = (u16*)(ws + (0ull));
  u16* Xk   = (u16*)(ws + (8ull << 20));
  u16* Xv   = (u16*)(ws + (16ull << 20));
  u16* WqT  = (u16*)(ws + (24ull << 20));
  u16* WkT  = (u16*)(ws + (26ull << 20));
  u16* WvT  = (u16*)(ws + (28ull << 20));
  u16* WoT  = (u16*)(ws + (30ull << 20));
  u16* q_ws = (u16*)(ws + (32ull << 20));
  u16* k_ws = (u16*)(ws + (40ull << 20));
  u16* vT_ws= (u16*)(ws + (48ull << 20));
  u16* x_ws = (u16*)(ws + (56ull << 20));
  u32* mb   = (u32*)(ws + (16ull << 20));   // overlays Xv (dead after proj)

  ra_convert_in<<<dim3(1024, 3), 256, 0, stream>>>(query, key_, value, Xq, Xk, Xv);
  ra_transpose_w<<<dim3(32, 32, 4), dim3(32, 8), 0, stream>>>(Wq, Wk, Wv, Wo, WqT, WkT, WvT, WoT);
  ra_proj_gemm<<<dim3(32, 8, 3), 256, 0, stream>>>(Xq, Xk, Xv, WqT, WkT, WvT, bq, bk, bv,
                                                   q_ws, k_ws, vT_ws);
  ra_mask_pack<<<16384, 256, 0, stream>>>(mask, mb);
  ra_attn<<<dim3(64, 4), 1024, 0, stream>>>(q_ws, k_ws, vT_ws, mb, rel, x_ws);
  ra_out_gemm<<<dim3(32, 8), 256, 0, stream>>>(x_ws, WoT, bo, out);
}